// Round 1
// baseline (2862.867 us; speedup 1.0000x reference)
//
#include <hip/hip_runtime.h>

#define HIDDEN 128

// ---------------------------------------------------------------------------
// Stage 2: per-edge scatter. 32 lanes per edge, float4 per lane (128 floats).
// agg[src] += p * hidden[tgt]
// ---------------------------------------------------------------------------
__global__ __launch_bounds__(256) void scatter_k(
    const float* __restrict__ prob,
    const float* __restrict__ hidden,
    const int*   __restrict__ ei,     // [2, E] row-major: src = ei[e], tgt = ei[E+e]
    float*       __restrict__ agg,
    int E)
{
    int t = blockIdx.x * blockDim.x + threadIdx.x;
    int e = t >> 5;
    if (e >= E) return;
    int l = t & 31;

    int   src = ei[e];
    int   tgt = ei[E + e];
    float p   = prob[e];

    float4 v = ((const float4*)(hidden + (size_t)tgt * HIDDEN))[l];
    float* ap = agg + (size_t)src * HIDDEN + l * 4;
    atomicAdd(ap + 0, v.x * p);
    atomicAdd(ap + 1, v.y * p);
    atomicAdd(ap + 2, v.z * p);
    atomicAdd(ap + 3, v.w * p);
}

// ---------------------------------------------------------------------------
// Stage 3: out = agg @ W^T + b.  Persistent blocks; each block owns one
// 64-output half of W (transposed, 32 KB LDS) and sweeps 32-row tiles of agg
// (transposed into LDS, stride 36 to keep float2 reads aligned + conflict-lite).
// Thread = (oq, rg): 4 outputs (float4) x 2 rows. Per k: 1 ds_read_b128 (W)
// + 1 ds_read_b64 (A) -> 8 FMAs.  LDS total 51.2 KB -> 3 blocks/CU.
// ---------------------------------------------------------------------------
__global__ __launch_bounds__(256) void gemm_k(
    const float* __restrict__ agg,
    const float* __restrict__ W,      // [128,128], out = agg @ W^T
    const float* __restrict__ bias,   // [128]
    float*       __restrict__ out,
    int N)
{
    __shared__ float wt[128 * 64];    // wt[k*64 + o'], o' = o - oh*64
    __shared__ float at[128 * 36];    // at[k*36 + r],  r = 0..31

    const int tid = threadIdx.x;
    const int oh  = blockIdx.x & 1;   // which 64-output half
    const int oq  = tid & 15;         // float4 index within the half
    const int rg  = tid >> 4;         // 0..15, two rows each

    // Stage W-half transposed into LDS (global reads coalesced over k).
    for (int i = tid; i < 64 * 128; i += 256) {
        int o = i >> 7;               // 0..63
        int k = i & 127;
        wt[k * 64 + o] = W[(size_t)(oh * 64 + o) * 128 + k];
    }

    const float4 bv = ((const float4*)bias)[oh * 16 + oq];
    const int row_tiles = gridDim.x >> 1;

    for (int n0 = (blockIdx.x >> 1) * 32; n0 < N; n0 += row_tiles * 32) {
        __syncthreads();  // protects previous tile's reads; also fences wt staging on iter 0
        for (int i = tid; i < 32 * 128; i += 256) {
            int r = i >> 7;
            int k = i & 127;
            int n = n0 + r;
            at[k * 36 + r] = (n < N) ? agg[(size_t)n * 128 + k] : 0.0f;
        }
        __syncthreads();

        float4 acc0 = make_float4(0.f, 0.f, 0.f, 0.f);
        float4 acc1 = make_float4(0.f, 0.f, 0.f, 0.f);
        #pragma unroll 8
        for (int k = 0; k < 128; ++k) {
            float4 w4 = *(const float4*)&wt[k * 64 + oq * 4];
            float2 a2 = *(const float2*)&at[k * 36 + rg * 2];
            acc0.x += w4.x * a2.x; acc0.y += w4.y * a2.x;
            acc0.z += w4.z * a2.x; acc0.w += w4.w * a2.x;
            acc1.x += w4.x * a2.y; acc1.y += w4.y * a2.y;
            acc1.z += w4.z * a2.y; acc1.w += w4.w * a2.y;
        }

        int n_a = n0 + rg * 2;
        int n_b = n_a + 1;
        if (n_a < N) {
            float4 r = make_float4(acc0.x + bv.x, acc0.y + bv.y,
                                   acc0.z + bv.z, acc0.w + bv.w);
            ((float4*)(out + (size_t)n_a * HIDDEN + oh * 64))[oq] = r;
        }
        if (n_b < N) {
            float4 r = make_float4(acc1.x + bv.x, acc1.y + bv.y,
                                   acc1.z + bv.z, acc1.w + bv.w);
            ((float4*)(out + (size_t)n_b * HIDDEN + oh * 64))[oq] = r;
        }
    }
}

extern "C" void kernel_launch(void* const* d_in, const int* in_sizes, int n_in,
                              void* d_out, int out_size, void* d_ws, size_t ws_size,
                              hipStream_t stream)
{
    const float* prob   = (const float*)d_in[0];
    const float* hidden = (const float*)d_in[1];
    const int*   ei     = (const int*)  d_in[2];
    const float* W      = (const float*)d_in[3];
    const float* bias   = (const float*)d_in[4];
    float*       out    = (float*)d_out;

    const int E = in_sizes[0];
    const int N = in_sizes[1] / HIDDEN;

    float* agg = (float*)d_ws;   // [N,128] fp32 accumulator (51.2 MB)

    hipMemsetAsync(agg, 0, (size_t)N * HIDDEN * sizeof(float), stream);

    long long total = (long long)E * 32;
    int blocks = (int)((total + 255) / 256);
    scatter_k<<<blocks, 256, 0, stream>>>(prob, hidden, ei, agg, E);

    gemm_k<<<768, 256, 0, stream>>>(agg, W, bias, out, N);
}

// Round 3
// 697.739 us; speedup vs baseline: 4.1031x; 4.1031x over previous
//
#include <hip/hip_runtime.h>

#define HIDDEN 128

static __device__ __forceinline__ ushort f2bf(float f) {
    uint u = __float_as_uint(f);
    uint r = (u + 0x7fffu + ((u >> 16) & 1u)) >> 16;   // round-to-nearest-even
    return (ushort)r;
}

// ---------------------------------------------------------------------------
// CSR build stage 1: per-node degree count (int atomics, cheap)
// ---------------------------------------------------------------------------
__global__ __launch_bounds__(256) void count_k(
    const int* __restrict__ ei, int* __restrict__ cnt, int E)
{
    int e = blockIdx.x * blockDim.x + threadIdx.x;
    if (e < E) atomicAdd(&cnt[ei[e]], 1);
}

// ---------------------------------------------------------------------------
// CSR build stage 2: single-block exclusive scan of cnt[N] -> offs, cur
// ---------------------------------------------------------------------------
__global__ __launch_bounds__(1024) void scan_k(
    const int* __restrict__ cnt, int* __restrict__ offs, int* __restrict__ cur,
    int N, int E)
{
    __shared__ int sums[1024];
    const int tid = threadIdx.x;
    const int chunk = (N + 1023) / 1024;
    const int i0 = tid * chunk;
    const int i1 = min(i0 + chunk, N);

    int s = 0;
    for (int i = i0; i < i1; ++i) s += cnt[i];
    sums[tid] = s;
    __syncthreads();

    for (int off = 1; off < 1024; off <<= 1) {
        int v = (tid >= off) ? sums[tid - off] : 0;
        __syncthreads();
        sums[tid] += v;
        __syncthreads();
    }
    int run = (tid == 0) ? 0 : sums[tid - 1];

    for (int i = i0; i < i1; ++i) {
        offs[i] = run;
        cur[i]  = run;
        run += cnt[i];
    }
    if (tid == 1023) offs[N] = E;
}

// ---------------------------------------------------------------------------
// CSR build stage 3: bucket fill. edata[pos] = {tgt, p}
// ---------------------------------------------------------------------------
__global__ __launch_bounds__(256) void fill_k(
    const int* __restrict__ ei, const float* __restrict__ prob,
    int* __restrict__ cur, int2* __restrict__ edata, int E)
{
    int e = blockIdx.x * blockDim.x + threadIdx.x;
    if (e >= E) return;
    int src = ei[e];
    int tgt = ei[E + e];
    int pos = atomicAdd(&cur[src], 1);
    edata[pos] = make_int2(tgt, __float_as_int(prob[e]));
}

// ---------------------------------------------------------------------------
// hp = bf16(hidden @ W^T)  (no bias; bias applied in agg_k).
// ---------------------------------------------------------------------------
__global__ __launch_bounds__(256) void gemm_k(
    const float* __restrict__ A,      // hidden [N,128]
    const float* __restrict__ W,      // [128,128]
    ushort*      __restrict__ hp,     // [N,128] bf16
    int N)
{
    __shared__ float wt[128 * 64];    // wt[k*64 + o']
    __shared__ float at[128 * 36];    // at[k*36 + r]

    const int tid = threadIdx.x;
    const int oh  = blockIdx.x & 1;
    const int oq  = tid & 15;
    const int rg  = tid >> 4;

    for (int i = tid; i < 64 * 128; i += 256) {
        int o = i >> 7;
        int k = i & 127;
        wt[k * 64 + o] = W[(size_t)(oh * 64 + o) * 128 + k];
    }

    const int row_tiles = gridDim.x >> 1;

    for (int n0 = (blockIdx.x >> 1) * 32; n0 < N; n0 += row_tiles * 32) {
        __syncthreads();
        for (int i = tid; i < 32 * 128; i += 256) {
            int r = i >> 7;
            int k = i & 127;
            int n = n0 + r;
            at[k * 36 + r] = (n < N) ? A[(size_t)n * 128 + k] : 0.0f;
        }
        __syncthreads();

        float4 acc0 = make_float4(0.f, 0.f, 0.f, 0.f);
        float4 acc1 = make_float4(0.f, 0.f, 0.f, 0.f);
        #pragma unroll 8
        for (int k = 0; k < 128; ++k) {
            float4 w4 = *(const float4*)&wt[k * 64 + oq * 4];
            float2 a2 = *(const float2*)&at[k * 36 + rg * 2];
            acc0.x += w4.x * a2.x; acc0.y += w4.y * a2.x;
            acc0.z += w4.z * a2.x; acc0.w += w4.w * a2.x;
            acc1.x += w4.x * a2.y; acc1.y += w4.y * a2.y;
            acc1.z += w4.z * a2.y; acc1.w += w4.w * a2.y;
        }

        int n_a = n0 + rg * 2;
        int n_b = n_a + 1;
        if (n_a < N) {
            ushort4 r; r.x = f2bf(acc0.x); r.y = f2bf(acc0.y);
            r.z = f2bf(acc0.z); r.w = f2bf(acc0.w);
            ((ushort4*)(hp + (size_t)n_a * HIDDEN + oh * 64))[oq] = r;
        }
        if (n_b < N) {
            ushort4 r; r.x = f2bf(acc1.x); r.y = f2bf(acc1.y);
            r.z = f2bf(acc1.z); r.w = f2bf(acc1.w);
            ((ushort4*)(hp + (size_t)n_b * HIDDEN + oh * 64))[oq] = r;
        }
    }
}

// ---------------------------------------------------------------------------
// out[n] = bias + sum_{e in CSR[n]} p_e * hp[tgt_e]
// One 64-lane wave per node; lane = float2 slice. bf16 gather, fp32 accum.
// ---------------------------------------------------------------------------
__global__ __launch_bounds__(256) void agg_k(
    const int*  __restrict__ offs,
    const int2* __restrict__ edata,
    const ushort* __restrict__ hp,
    const float* __restrict__ bias,
    float*       __restrict__ out,
    int N)
{
    int wave = (blockIdx.x * blockDim.x + threadIdx.x) >> 6;
    int l    = threadIdx.x & 63;
    if (wave >= N) return;

    float2 acc = ((const float2*)bias)[l];
    int beg = offs[wave];
    int end = offs[wave + 1];
    const uint* hpw = (const uint*)hp;   // bf16x2 per uint

    int i = beg;
    for (; i + 2 <= end; i += 2) {
        int2 d0 = edata[i];
        int2 d1 = edata[i + 1];
        uint h0 = hpw[(size_t)d0.x * 64 + l];
        uint h1 = hpw[(size_t)d1.x * 64 + l];
        float p0 = __int_as_float(d0.y);
        float p1 = __int_as_float(d1.y);
        acc.x += p0 * __uint_as_float(h0 << 16);
        acc.y += p0 * __uint_as_float(h0 & 0xffff0000u);
        acc.x += p1 * __uint_as_float(h1 << 16);
        acc.y += p1 * __uint_as_float(h1 & 0xffff0000u);
    }
    if (i < end) {
        int2 d = edata[i];
        uint h = hpw[(size_t)d.x * 64 + l];
        float p = __int_as_float(d.y);
        acc.x += p * __uint_as_float(h << 16);
        acc.y += p * __uint_as_float(h & 0xffff0000u);
    }

    ((float2*)(out + (size_t)wave * HIDDEN))[l] = acc;
}

extern "C" void kernel_launch(void* const* d_in, const int* in_sizes, int n_in,
                              void* d_out, int out_size, void* d_ws, size_t ws_size,
                              hipStream_t stream)
{
    const float* prob   = (const float*)d_in[0];
    const float* hidden = (const float*)d_in[1];
    const int*   ei     = (const int*)  d_in[2];
    const float* W      = (const float*)d_in[3];
    const float* bias   = (const float*)d_in[4];
    float*       out    = (float*)d_out;

    const int E = in_sizes[0];
    const int N = in_sizes[1] / HIDDEN;

    // Workspace layout (16B-aligned sections):
    char* w = (char*)d_ws;
    int*  cnt  = (int*)w;                         // N
    int*  offs = cnt + N;                         // N+1
    int*  cur  = offs + N + 1;                    // N
    size_t ib = ((size_t)(3 * N + 1) * 4 + 15) & ~(size_t)15;
    int2*   edata = (int2*)(w + ib);              // E * 8B
    ushort* hp    = (ushort*)(w + ib + (size_t)E * 8);  // N*128 bf16

    hipMemsetAsync(cnt, 0, (size_t)N * sizeof(int), stream);

    int eb = (E + 255) / 256;
    count_k<<<eb, 256, 0, stream>>>(ei, cnt, E);
    scan_k<<<1, 1024, 0, stream>>>(cnt, offs, cur, N, E);
    fill_k<<<eb, 256, 0, stream>>>(ei, prob, cur, edata, E);
    gemm_k<<<768, 256, 0, stream>>>(hidden, W, hp, N);
    // one 64-lane wave per node: 256-thread block = 4 nodes
    agg_k<<<(N + 3) / 4, 256, 0, stream>>>(offs, edata, hp, bias, out, N);
}

// Round 4
// 460.019 us; speedup vs baseline: 6.2234x; 1.5168x over previous
//
#include <hip/hip_runtime.h>

#define HIDDEN 128

static __device__ __forceinline__ ushort f2bf(float f) {
    uint u = __float_as_uint(f);
    uint r = (u + 0x7fffu + ((u >> 16) & 1u)) >> 16;   // round-to-nearest-even
    return (ushort)r;
}

// ---------------------------------------------------------------------------
// CSR build stage 1: per-node degree count (int atomics, cheap)
// ---------------------------------------------------------------------------
__global__ __launch_bounds__(256) void count_k(
    const int* __restrict__ ei, int* __restrict__ cnt, int E)
{
    int e = blockIdx.x * blockDim.x + threadIdx.x;
    if (e < E) atomicAdd(&cnt[ei[e]], 1);
}

// ---------------------------------------------------------------------------
// Hierarchical scan, phase 1: per-block (1024-wide) exclusive scan of cnt.
// offs[g] = block-local exclusive prefix; bsum[b] = block total.
// ---------------------------------------------------------------------------
__global__ __launch_bounds__(1024) void scan1_k(
    const int* __restrict__ cnt, int* __restrict__ offs, int* __restrict__ bsum,
    int N)
{
    __shared__ int s[1024];
    const int t = threadIdx.x;
    const int g = blockIdx.x * 1024 + t;
    int x = (g < N) ? cnt[g] : 0;
    s[t] = x;
    __syncthreads();
    #pragma unroll
    for (int off = 1; off < 1024; off <<= 1) {
        int v = (t >= off) ? s[t - off] : 0;
        __syncthreads();
        s[t] += v;
        __syncthreads();
    }
    if (g < N) offs[g] = s[t] - x;          // exclusive
    if (t == 1023) bsum[blockIdx.x] = s[1023];
}

// ---------------------------------------------------------------------------
// Phase 2: exclusive scan of block sums (B <= 1024), one block.
// ---------------------------------------------------------------------------
__global__ __launch_bounds__(1024) void scan2_k(
    const int* __restrict__ bsum, int* __restrict__ boff,
    int* __restrict__ offs, int B, int N, int E)
{
    __shared__ int s[1024];
    const int t = threadIdx.x;
    int x = (t < B) ? bsum[t] : 0;
    s[t] = x;
    __syncthreads();
    #pragma unroll
    for (int off = 1; off < 1024; off <<= 1) {
        int v = (t >= off) ? s[t - off] : 0;
        __syncthreads();
        s[t] += v;
        __syncthreads();
    }
    if (t < B) boff[t] = s[t] - x;          // exclusive
    if (t == 0) offs[N] = E;
}

// ---------------------------------------------------------------------------
// Phase 3: add block offsets; mirror into cur.
// ---------------------------------------------------------------------------
__global__ __launch_bounds__(1024) void scan3_k(
    int* __restrict__ offs, int* __restrict__ cur,
    const int* __restrict__ boff, int N)
{
    int g = blockIdx.x * 1024 + threadIdx.x;
    if (g < N) {
        int v = offs[g] + boff[blockIdx.x];
        offs[g] = v;
        cur[g]  = v;
    }
}

// ---------------------------------------------------------------------------
// CSR build stage 3: bucket fill. edata[pos] = {tgt, p}
// ---------------------------------------------------------------------------
__global__ __launch_bounds__(256) void fill_k(
    const int* __restrict__ ei, const float* __restrict__ prob,
    int* __restrict__ cur, int2* __restrict__ edata, int E)
{
    int e = blockIdx.x * blockDim.x + threadIdx.x;
    if (e >= E) return;
    int src = ei[e];
    int tgt = ei[E + e];
    int pos = atomicAdd(&cur[src], 1);
    edata[pos] = make_int2(tgt, __float_as_int(prob[e]));
}

// ---------------------------------------------------------------------------
// hp = bf16(hidden @ W^T)  (no bias; bias applied in agg_k).
// ---------------------------------------------------------------------------
__global__ __launch_bounds__(256) void gemm_k(
    const float* __restrict__ A,      // hidden [N,128]
    const float* __restrict__ W,      // [128,128]
    ushort*      __restrict__ hp,     // [N,128] bf16
    int N)
{
    __shared__ float wt[128 * 64];    // wt[k*64 + o']
    __shared__ float at[128 * 36];    // at[k*36 + r]

    const int tid = threadIdx.x;
    const int oh  = blockIdx.x & 1;
    const int oq  = tid & 15;
    const int rg  = tid >> 4;

    for (int i = tid; i < 64 * 128; i += 256) {
        int o = i >> 7;
        int k = i & 127;
        wt[k * 64 + o] = W[(size_t)(oh * 64 + o) * 128 + k];
    }

    const int row_tiles = gridDim.x >> 1;

    for (int n0 = (blockIdx.x >> 1) * 32; n0 < N; n0 += row_tiles * 32) {
        __syncthreads();
        for (int i = tid; i < 32 * 128; i += 256) {
            int r = i >> 7;
            int k = i & 127;
            int n = n0 + r;
            at[k * 36 + r] = (n < N) ? A[(size_t)n * 128 + k] : 0.0f;
        }
        __syncthreads();

        float4 acc0 = make_float4(0.f, 0.f, 0.f, 0.f);
        float4 acc1 = make_float4(0.f, 0.f, 0.f, 0.f);
        #pragma unroll 8
        for (int k = 0; k < 128; ++k) {
            float4 w4 = *(const float4*)&wt[k * 64 + oq * 4];
            float2 a2 = *(const float2*)&at[k * 36 + rg * 2];
            acc0.x += w4.x * a2.x; acc0.y += w4.y * a2.x;
            acc0.z += w4.z * a2.x; acc0.w += w4.w * a2.x;
            acc1.x += w4.x * a2.y; acc1.y += w4.y * a2.y;
            acc1.z += w4.z * a2.y; acc1.w += w4.w * a2.y;
        }

        int n_a = n0 + rg * 2;
        int n_b = n_a + 1;
        if (n_a < N) {
            ushort4 r; r.x = f2bf(acc0.x); r.y = f2bf(acc0.y);
            r.z = f2bf(acc0.z); r.w = f2bf(acc0.w);
            ((ushort4*)(hp + (size_t)n_a * HIDDEN + oh * 64))[oq] = r;
        }
        if (n_b < N) {
            ushort4 r; r.x = f2bf(acc1.x); r.y = f2bf(acc1.y);
            r.z = f2bf(acc1.z); r.w = f2bf(acc1.w);
            ((ushort4*)(hp + (size_t)n_b * HIDDEN + oh * 64))[oq] = r;
        }
    }
}

// ---------------------------------------------------------------------------
// out[n] = bias + sum_{e in CSR[n]} p_e * hp[tgt_e]
// One 64-lane wave per node; lane = float2 slice. bf16 gather, fp32 accum.
// ---------------------------------------------------------------------------
__global__ __launch_bounds__(256) void agg_k(
    const int*  __restrict__ offs,
    const int2* __restrict__ edata,
    const ushort* __restrict__ hp,
    const float* __restrict__ bias,
    float*       __restrict__ out,
    int N)
{
    int wave = (blockIdx.x * blockDim.x + threadIdx.x) >> 6;
    int l    = threadIdx.x & 63;
    if (wave >= N) return;

    float2 acc = ((const float2*)bias)[l];
    int beg = offs[wave];
    int end = offs[wave + 1];
    const uint* hpw = (const uint*)hp;   // bf16x2 per uint

    int i = beg;
    for (; i + 2 <= end; i += 2) {
        int2 d0 = edata[i];
        int2 d1 = edata[i + 1];
        uint h0 = hpw[(size_t)d0.x * 64 + l];
        uint h1 = hpw[(size_t)d1.x * 64 + l];
        float p0 = __int_as_float(d0.y);
        float p1 = __int_as_float(d1.y);
        acc.x += p0 * __uint_as_float(h0 << 16);
        acc.y += p0 * __uint_as_float(h0 & 0xffff0000u);
        acc.x += p1 * __uint_as_float(h1 << 16);
        acc.y += p1 * __uint_as_float(h1 & 0xffff0000u);
    }
    if (i < end) {
        int2 d = edata[i];
        uint h = hpw[(size_t)d.x * 64 + l];
        float p = __int_as_float(d.y);
        acc.x += p * __uint_as_float(h << 16);
        acc.y += p * __uint_as_float(h & 0xffff0000u);
    }

    ((float2*)(out + (size_t)wave * HIDDEN))[l] = acc;
}

extern "C" void kernel_launch(void* const* d_in, const int* in_sizes, int n_in,
                              void* d_out, int out_size, void* d_ws, size_t ws_size,
                              hipStream_t stream)
{
    const float* prob   = (const float*)d_in[0];
    const float* hidden = (const float*)d_in[1];
    const int*   ei     = (const int*)  d_in[2];
    const float* W      = (const float*)d_in[3];
    const float* bias   = (const float*)d_in[4];
    float*       out    = (float*)d_out;

    const int E = in_sizes[0];
    const int N = in_sizes[1] / HIDDEN;
    const int B = (N + 1023) / 1024;   // scan blocks (98 for N=100k)

    // Workspace layout (16B-aligned sections):
    char* w = (char*)d_ws;
    int*  cnt  = (int*)w;                         // N
    int*  offs = cnt + N;                         // N+1
    int*  cur  = offs + N + 1;                    // N
    int*  bsum = cur + N;                         // B
    int*  boff = bsum + B;                        // B
    size_t ib = ((size_t)(3 * N + 1 + 2 * B) * 4 + 15) & ~(size_t)15;
    int2*   edata = (int2*)(w + ib);              // E * 8B
    ushort* hp    = (ushort*)(w + ib + (size_t)E * 8);  // N*128 bf16

    hipMemsetAsync(cnt, 0, (size_t)N * sizeof(int), stream);

    int eb = (E + 255) / 256;
    count_k<<<eb, 256, 0, stream>>>(ei, cnt, E);
    scan1_k<<<B, 1024, 0, stream>>>(cnt, offs, bsum, N);
    scan2_k<<<1, 1024, 0, stream>>>(bsum, boff, offs, B, N, E);
    scan3_k<<<B, 1024, 0, stream>>>(offs, cur, boff, N);
    fill_k<<<eb, 256, 0, stream>>>(ei, prob, cur, edata, E);
    gemm_k<<<768, 256, 0, stream>>>(hidden, W, hp, N);
    // one 64-lane wave per node: 256-thread block = 4 nodes
    agg_k<<<(N + 3) / 4, 256, 0, stream>>>(offs, edata, hp, bias, out, N);
}

// Round 5
// 454.656 us; speedup vs baseline: 6.2968x; 1.0118x over previous
//
#include <hip/hip_runtime.h>

#define HIDDEN 128

static __device__ __forceinline__ ushort f2bf(float f) {
    uint u = __float_as_uint(f);
    uint r = (u + 0x7fffu + ((u >> 16) & 1u)) >> 16;   // round-to-nearest-even
    return (ushort)r;
}

// ---------------------------------------------------------------------------
// CSR build stage 1: per-node degree count (int atomics, cheap)
// ---------------------------------------------------------------------------
__global__ __launch_bounds__(256) void count_k(
    const int* __restrict__ ei, int* __restrict__ cnt, int E)
{
    int e = blockIdx.x * blockDim.x + threadIdx.x;
    if (e < E) atomicAdd(&cnt[ei[e]], 1);
}

// ---------------------------------------------------------------------------
// Hierarchical scan (3 phases)
// ---------------------------------------------------------------------------
__global__ __launch_bounds__(1024) void scan1_k(
    const int* __restrict__ cnt, int* __restrict__ offs, int* __restrict__ bsum,
    int N)
{
    __shared__ int s[1024];
    const int t = threadIdx.x;
    const int g = blockIdx.x * 1024 + t;
    int x = (g < N) ? cnt[g] : 0;
    s[t] = x;
    __syncthreads();
    #pragma unroll
    for (int off = 1; off < 1024; off <<= 1) {
        int v = (t >= off) ? s[t - off] : 0;
        __syncthreads();
        s[t] += v;
        __syncthreads();
    }
    if (g < N) offs[g] = s[t] - x;
    if (t == 1023) bsum[blockIdx.x] = s[1023];
}

__global__ __launch_bounds__(1024) void scan2_k(
    const int* __restrict__ bsum, int* __restrict__ boff,
    int* __restrict__ offs, int B, int N, int E)
{
    __shared__ int s[1024];
    const int t = threadIdx.x;
    int x = (t < B) ? bsum[t] : 0;
    s[t] = x;
    __syncthreads();
    #pragma unroll
    for (int off = 1; off < 1024; off <<= 1) {
        int v = (t >= off) ? s[t - off] : 0;
        __syncthreads();
        s[t] += v;
        __syncthreads();
    }
    if (t < B) boff[t] = s[t] - x;
    if (t == 0) offs[N] = E;
}

__global__ __launch_bounds__(1024) void scan3_k(
    int* __restrict__ offs, int* __restrict__ cur,
    const int* __restrict__ boff, int N)
{
    int g = blockIdx.x * 1024 + threadIdx.x;
    if (g < N) {
        int v = offs[g] + boff[blockIdx.x];
        offs[g] = v;
        cur[g]  = v;
    }
}

// ---------------------------------------------------------------------------
// CSR build stage 3: bucket fill, 4B packed payload (tgt:17 | p:15)
// ---------------------------------------------------------------------------
__global__ __launch_bounds__(256) void fill_k(
    const int* __restrict__ ei, const float* __restrict__ prob,
    int* __restrict__ cur, uint* __restrict__ edata, int E)
{
    int e = blockIdx.x * blockDim.x + threadIdx.x;
    if (e >= E) return;
    int  src = ei[e];
    uint tgt = (uint)ei[E + e];
    int  pos = atomicAdd(&cur[src], 1);
    int  p15 = (int)(prob[e] * 32768.0f + 0.5f);
    p15 = min(p15, 32767);
    edata[pos] = (tgt << 15) | (uint)p15;
}

// ---------------------------------------------------------------------------
// hp = bf16(hidden @ W^T).  One block = one 128-row x 128-out tile.
// LDS: wt[k*128+o] (64KB, transposed W), at[k*132+r] (67.6KB, transposed A).
// Thread = 8 rows x 8 outs: per k reads 64B LDS -> 64 FMA (1 B/MAC).
// ---------------------------------------------------------------------------
__global__ __launch_bounds__(256) void gemm_k(
    const float* __restrict__ A,      // hidden [N,128]
    const float* __restrict__ W,      // [128,128]
    ushort*      __restrict__ hp,     // [N,128] bf16
    int N)
{
    __shared__ float wt[128 * 128];   // [k][o]
    __shared__ float at[128 * 132];   // [k][r], stride 132 (write 2-way, read clean)

    const int tid = threadIdx.x;
    const int r5  = tid & 31;         // fast lane index -> conflict-free LDS writes
    const int c3  = tid >> 5;         // 0..7 float4-col group
    const int n0  = blockIdx.x * 128;

    // Stage W [o][k] -> wt[k][o]   (o = r5+32*ri, float4 k-col = c3+8*ci)
    #pragma unroll
    for (int ri = 0; ri < 4; ++ri) {
        int o = r5 + 32 * ri;
        #pragma unroll
        for (int ci = 0; ci < 4; ++ci) {
            int c = c3 + 8 * ci;
            float4 v = ((const float4*)(W + (size_t)o * 128))[c];
            int k = 4 * c;
            wt[(k + 0) * 128 + o] = v.x;
            wt[(k + 1) * 128 + o] = v.y;
            wt[(k + 2) * 128 + o] = v.z;
            wt[(k + 3) * 128 + o] = v.w;
        }
    }
    // Stage A-tile [r][k] -> at[k][r]
    #pragma unroll
    for (int ri = 0; ri < 4; ++ri) {
        int r = r5 + 32 * ri;
        int n = n0 + r;
        #pragma unroll
        for (int ci = 0; ci < 4; ++ci) {
            int c = c3 + 8 * ci;
            float4 v = (n < N) ? ((const float4*)(A + (size_t)n * 128))[c]
                               : make_float4(0.f, 0.f, 0.f, 0.f);
            int k = 4 * c;
            at[(k + 0) * 132 + r] = v.x;
            at[(k + 1) * 132 + r] = v.y;
            at[(k + 2) * 132 + r] = v.z;
            at[(k + 3) * 132 + r] = v.w;
        }
    }
    __syncthreads();

    const int og = tid & 15;          // out group: outs og*8..+7
    const int rg = tid >> 4;          // row group: rows rg*8..+7

    float acc[8][8];
    #pragma unroll
    for (int r = 0; r < 8; ++r)
        #pragma unroll
        for (int o = 0; o < 8; ++o) acc[r][o] = 0.f;

    #pragma unroll 2
    for (int k = 0; k < 128; ++k) {
        float4 w0 = *(const float4*)&wt[k * 128 + og * 8];
        float4 w1 = *(const float4*)&wt[k * 128 + og * 8 + 4];
        float4 a0 = *(const float4*)&at[k * 132 + rg * 8];
        float4 a1 = *(const float4*)&at[k * 132 + rg * 8 + 4];
        float wv[8] = {w0.x, w0.y, w0.z, w0.w, w1.x, w1.y, w1.z, w1.w};
        float av[8] = {a0.x, a0.y, a0.z, a0.w, a1.x, a1.y, a1.z, a1.w};
        #pragma unroll
        for (int r = 0; r < 8; ++r)
            #pragma unroll
            for (int o = 0; o < 8; ++o)
                acc[r][o] += av[r] * wv[o];
    }

    #pragma unroll
    for (int r = 0; r < 8; ++r) {
        int n = n0 + rg * 8 + r;
        if (n < N) {
            ushort4 u0, u1;
            u0.x = f2bf(acc[r][0]); u0.y = f2bf(acc[r][1]);
            u0.z = f2bf(acc[r][2]); u0.w = f2bf(acc[r][3]);
            u1.x = f2bf(acc[r][4]); u1.y = f2bf(acc[r][5]);
            u1.z = f2bf(acc[r][6]); u1.w = f2bf(acc[r][7]);
            ushort4* dst = (ushort4*)(hp + (size_t)n * 128 + og * 8);
            dst[0] = u0;
            dst[1] = u1;
        }
    }
}

// ---------------------------------------------------------------------------
// out[n] = bias + sum_{e in CSR[n]} p_e * hp[tgt_e]
// One 64-lane wave per node; lane = float2 slice. 4x unrolled.
// ---------------------------------------------------------------------------
__global__ __launch_bounds__(256) void agg_k(
    const int*  __restrict__ offs,
    const uint* __restrict__ edata,
    const ushort* __restrict__ hp,
    const float* __restrict__ bias,
    float*       __restrict__ out,
    int N)
{
    int wave = (blockIdx.x * blockDim.x + threadIdx.x) >> 6;
    int l    = threadIdx.x & 63;
    if (wave >= N) return;

    float2 acc = ((const float2*)bias)[l];
    int beg = offs[wave];
    int end = offs[wave + 1];
    const uint* hpw = (const uint*)hp;   // bf16x2 per uint
    const float ps = 1.0f / 32768.0f;

    int i = beg;
    for (; i + 4 <= end; i += 4) {
        uint w0 = edata[i], w1 = edata[i + 1], w2 = edata[i + 2], w3 = edata[i + 3];
        uint h0 = hpw[(size_t)(w0 >> 15) * 64 + l];
        uint h1 = hpw[(size_t)(w1 >> 15) * 64 + l];
        uint h2 = hpw[(size_t)(w2 >> 15) * 64 + l];
        uint h3 = hpw[(size_t)(w3 >> 15) * 64 + l];
        float p0 = (float)(w0 & 0x7fffu) * ps;
        float p1 = (float)(w1 & 0x7fffu) * ps;
        float p2 = (float)(w2 & 0x7fffu) * ps;
        float p3 = (float)(w3 & 0x7fffu) * ps;
        acc.x += p0 * __uint_as_float(h0 << 16);
        acc.y += p0 * __uint_as_float(h0 & 0xffff0000u);
        acc.x += p1 * __uint_as_float(h1 << 16);
        acc.y += p1 * __uint_as_float(h1 & 0xffff0000u);
        acc.x += p2 * __uint_as_float(h2 << 16);
        acc.y += p2 * __uint_as_float(h2 & 0xffff0000u);
        acc.x += p3 * __uint_as_float(h3 << 16);
        acc.y += p3 * __uint_as_float(h3 & 0xffff0000u);
    }
    for (; i < end; ++i) {
        uint w = edata[i];
        uint h = hpw[(size_t)(w >> 15) * 64 + l];
        float p = (float)(w & 0x7fffu) * ps;
        acc.x += p * __uint_as_float(h << 16);
        acc.y += p * __uint_as_float(h & 0xffff0000u);
    }

    ((float2*)(out + (size_t)wave * HIDDEN))[l] = acc;
}

extern "C" void kernel_launch(void* const* d_in, const int* in_sizes, int n_in,
                              void* d_out, int out_size, void* d_ws, size_t ws_size,
                              hipStream_t stream)
{
    const float* prob   = (const float*)d_in[0];
    const float* hidden = (const float*)d_in[1];
    const int*   ei     = (const int*)  d_in[2];
    const float* W      = (const float*)d_in[3];
    const float* bias   = (const float*)d_in[4];
    float*       out    = (float*)d_out;

    const int E = in_sizes[0];
    const int N = in_sizes[1] / HIDDEN;
    const int B = (N + 1023) / 1024;

    // Workspace layout (16B-aligned sections):
    char* w = (char*)d_ws;
    int*  cnt  = (int*)w;                         // N
    int*  offs = cnt + N;                         // N+1
    int*  cur  = offs + N + 1;                    // N
    int*  bsum = cur + N;                         // B
    int*  boff = bsum + B;                        // B
    size_t ib = ((size_t)(3 * N + 1 + 2 * B) * 4 + 15) & ~(size_t)15;
    uint*   edata = (uint*)(w + ib);              // E * 4B packed
    ushort* hp    = (ushort*)(w + ib + (size_t)E * 4);  // N*128 bf16

    hipMemsetAsync(cnt, 0, (size_t)N * sizeof(int), stream);

    int eb = (E + 255) / 256;
    count_k<<<eb, 256, 0, stream>>>(ei, cnt, E);
    scan1_k<<<B, 1024, 0, stream>>>(cnt, offs, bsum, N);
    scan2_k<<<1, 1024, 0, stream>>>(bsum, boff, offs, B, N, E);
    scan3_k<<<B, 1024, 0, stream>>>(offs, cur, boff, N);
    fill_k<<<eb, 256, 0, stream>>>(ei, prob, cur, edata, E);
    gemm_k<<<(N + 127) / 128, 256, 0, stream>>>(hidden, W, hp, N);
    agg_k<<<(N + 3) / 4, 256, 0, stream>>>(offs, edata, hp, bias, out, N);
}